// Round 17
// baseline (2165.370 us; speedup 1.0000x reference)
//
#include <hip/hip_runtime.h>
#include <hip/hip_fp16.h>

#define B_ 2
#define H_ 16
#define N_ 2048
#define D_ 64

typedef __attribute__((ext_vector_type(8))) __bf16 bf16x8;
typedef __attribute__((ext_vector_type(4))) float f32x4;

__device__ __forceinline__ unsigned short f2bf_rn(float x) {
  unsigned u = __float_as_uint(x);
  unsigned r = (u + 0x7fffu + ((u >> 16) & 1u)) >> 16;
  return (unsigned short)r;
}
__device__ __forceinline__ float bf2f(unsigned short s) {
  return __uint_as_float(((unsigned)s) << 16);
}
__device__ __forceinline__ float comp4(const float4& v, int m) {
  return m == 0 ? v.x : m == 1 ? v.y : m == 2 ? v.z : v.w;
}

// ---------------------------------------------------------------------------
// Pass 1 (fast approx): S~[h][il][j] = 0.125 * (q1k1 + q1k2 + q2k1) via bf16
// MFMA 16x16x32, f32 accumulate.  (unchanged — field-proven)
// ---------------------------------------------------------------------------
__global__ __launch_bounds__(256) void qk_mfma(
    const float* __restrict__ q, const float* __restrict__ k,
    float* __restrict__ S, int bb, int i0, int SI) {
  const int h  = blockIdx.z;
  const int it = blockIdx.y * 64;
  const int jt = blockIdx.x * 64;
  __shared__ unsigned short q1s[64][72], q2s[64][72];
  __shared__ unsigned short k1s[64][72], k2s[64][72];
  const int t = threadIdx.x;
  const float* qb = q + (((size_t)bb * H_ + h) * N_ + (size_t)(i0 + it)) * D_;
  const float* kb = k + (((size_t)bb * H_ + h) * N_ + (size_t)jt) * D_;
#pragma unroll
  for (int l = 0; l < 4; ++l) {
    int e4 = t + l * 256;
    int row = e4 >> 4, c4 = e4 & 15;
    float4 xq = *(const float4*)(qb + (size_t)row * D_ + c4 * 4);
    float4 xk = *(const float4*)(kb + (size_t)row * D_ + c4 * 4);
    float qa[4] = {xq.x, xq.y, xq.z, xq.w};
    float ka[4] = {xk.x, xk.y, xk.z, xk.w};
#pragma unroll
    for (int m = 0; m < 4; ++m) {
      unsigned short h1 = f2bf_rn(qa[m]);
      unsigned short h2 = f2bf_rn(qa[m] - bf2f(h1));
      q1s[row][c4 * 4 + m] = h1;
      q2s[row][c4 * 4 + m] = h2;
      unsigned short g1 = f2bf_rn(ka[m]);
      unsigned short g2 = f2bf_rn(ka[m] - bf2f(g1));
      k1s[row][c4 * 4 + m] = g1;
      k2s[row][c4 * 4 + m] = g2;
    }
  }
  __syncthreads();
  const int lane = t & 63, wv = t >> 6;
  const int lr = lane & 15;
  const int lk = (lane >> 4) * 8;
  const int arow = wv * 16 + lr;
  f32x4 acc[4];
#pragma unroll
  for (int ct = 0; ct < 4; ++ct) acc[ct] = (f32x4){0.f, 0.f, 0.f, 0.f};
#pragma unroll
  for (int ks = 0; ks < 2; ++ks) {
    bf16x8 a1 = *(const bf16x8*)&q1s[arow][ks * 32 + lk];
    bf16x8 a2 = *(const bf16x8*)&q2s[arow][ks * 32 + lk];
#pragma unroll
    for (int ct = 0; ct < 4; ++ct) {
      bf16x8 b1 = *(const bf16x8*)&k1s[ct * 16 + lr][ks * 32 + lk];
      bf16x8 b2 = *(const bf16x8*)&k2s[ct * 16 + lr][ks * 32 + lk];
      acc[ct] = __builtin_amdgcn_mfma_f32_16x16x32_bf16(a1, b1, acc[ct], 0, 0, 0);
      acc[ct] = __builtin_amdgcn_mfma_f32_16x16x32_bf16(a1, b2, acc[ct], 0, 0, 0);
      acc[ct] = __builtin_amdgcn_mfma_f32_16x16x32_bf16(a2, b1, acc[ct], 0, 0, 0);
    }
  }
#pragma unroll
  for (int ct = 0; ct < 4; ++ct)
#pragma unroll
    for (int r = 0; r < 4; ++r) {
      int row = it + wv * 16 + (lane >> 4) * 4 + r;
      int col = jt + ct * 16 + lr;
      S[((size_t)h * SI + row) * N_ + col] = acc[ct][r] * 0.125f;
    }
}

__device__ inline float waveReduceSum(float x) {
#pragma unroll
  for (int off = 32; off > 0; off >>= 1) x += __shfl_xor(x, off, 64);
  return x;
}

__device__ inline float dec_u(unsigned uu) {
  unsigned bbv = (uu >> 31) ? (uu & 0x7fffffffu) : ~uu;
  return __uint_as_float(bbv);
}

// ---------------------------------------------------------------------------
// EXACT referee replica (R8-proven AVX512-FMA tree), serial in one lane.
// float4 loads (quarter-by-quarter), chain arithmetic bit-identical.
// ---------------------------------------------------------------------------
__device__ float np_score(
    const float* __restrict__ qg, const float* __restrict__ kg,
    const float* __restrict__ w_pre, const float* __restrict__ bias,
    int bb, int g, int ig, int j) {
  float T = 0.f;
  for (int h = 0; h < 16; ++h) {
    const float* qr = qg + (((size_t)bb * H_ + h) * N_ + ig) * (size_t)D_;
    const float* kr = kg + (((size_t)bb * H_ + h) * N_ + j) * (size_t)D_;
    float lacc[16];
    // quarter 3 (offset 48): tt = mul
    {
      const float4* q4 = (const float4*)(qr + 48);
      const float4* k4 = (const float4*)(kr + 48);
      float4 qa[4] = {q4[0], q4[1], q4[2], q4[3]};
      float4 kb4[4] = {k4[0], k4[1], k4[2], k4[3]};
#pragma unroll
      for (int l = 0; l < 16; ++l)
        lacc[l] = __fmul_rn(comp4(qa[l >> 2], l & 3), comp4(kb4[l >> 2], l & 3));
    }
    // quarters 2,1,0: fma descending
#pragma unroll
    for (int qq = 2; qq >= 0; --qq) {
      const float4* q4 = (const float4*)(qr + qq * 16);
      const float4* k4 = (const float4*)(kr + qq * 16);
      float4 qa[4] = {q4[0], q4[1], q4[2], q4[3]};
      float4 kb4[4] = {k4[0], k4[1], k4[2], k4[3]};
#pragma unroll
      for (int l = 0; l < 16; ++l)
        lacc[l] = __fmaf_rn(comp4(qa[l >> 2], l & 3), comp4(kb4[l >> 2], l & 3),
                            lacc[l]);
    }
    float u8[8];
#pragma unroll
    for (int l2 = 0; l2 < 8; ++l2) u8[l2] = __fadd_rn(lacc[l2], lacc[l2 + 8]);
    float u4[4];
#pragma unroll
    for (int l2 = 0; l2 < 4; ++l2) u4[l2] = __fadd_rn(u8[l2], u8[l2 + 4]);
    float dot = __fadd_rn(__fadd_rn(u4[0], u4[2]), __fadd_rn(u4[1], u4[3]));
    T = __fmaf_rn(w_pre[g * 16 + h], __fmul_rn(dot, 0.125f), T);
  }
  return __fadd_rn(T, bias[((size_t)g * N_ + ig) * N_ + j]);
}

// ---------------------------------------------------------------------------
// Pass 2 (v17 = v16 + XCD-aware swizzle): 256-thr block (4 waves); 1-D grid
// SI*4 decoded so all 4 g-quarter blocks of an il share bid%8 (same XCD ->
// S row-set L2-hot after first touch). Arithmetic/mapping identical to v16.
// ---------------------------------------------------------------------------
__global__ __launch_bounds__(256) void mid_kernel(
    const float* __restrict__ S, __half* __restrict__ A,
    const float* __restrict__ bias,
    const float* __restrict__ w_pre,
    const int* __restrict__ topk_p,
    const float* __restrict__ qg, const float* __restrict__ kg,
    int bb, int i0, int SI) {
  const int bid = blockIdx.x;
  const int SI8 = SI >> 3;
  const int hi = bid >> 3;            // y*SI8 + il/8
  const int yq = hi / SI8;
  const int il = (hi % SI8) * 8 + (bid & 7);
  const int ig = i0 + il;
  const int t = threadIdx.x;
  const int lane = t & 63, wv = t >> 6;
  const int g = yq * 4 + wv;
  const int K = *topk_p;
  __shared__ float repv_s[4][32];

  // ---- mix: stream h, accumulate 32 cols in registers ----
  float af[32];
#pragma unroll
  for (int c = 0; c < 32; ++c) af[c] = 0.f;
#pragma unroll 1
  for (int h = 0; h < 16; ++h) {
    const float w = w_pre[g * 16 + h];
    const float* Sr = S + ((size_t)h * SI + il) * N_;
#pragma unroll
    for (int c4 = 0; c4 < 8; ++c4) {
      float4 s4 = *(const float4*)&Sr[lane * 4 + 256 * c4];
      af[c4 * 4 + 0] = __fmaf_rn(w, s4.x, af[c4 * 4 + 0]);
      af[c4 * 4 + 1] = __fmaf_rn(w, s4.y, af[c4 * 4 + 1]);
      af[c4 * 4 + 2] = __fmaf_rn(w, s4.z, af[c4 * 4 + 2]);
      af[c4 * 4 + 3] = __fmaf_rn(w, s4.w, af[c4 * 4 + 3]);
    }
  }
  unsigned u[32];
  {
    const float* Br = bias + ((size_t)g * N_ + ig) * N_;
#pragma unroll
    for (int c4 = 0; c4 < 8; ++c4) {
      float4 bv = *(const float4*)&Br[lane * 4 + 256 * c4];
      float x0 = __fadd_rn(af[c4 * 4 + 0], bv.x);
      float x1 = __fadd_rn(af[c4 * 4 + 1], bv.y);
      float x2 = __fadd_rn(af[c4 * 4 + 2], bv.z);
      float x3 = __fadd_rn(af[c4 * 4 + 3], bv.w);
      unsigned b0 = __float_as_uint(x0), b1 = __float_as_uint(x1);
      unsigned b2 = __float_as_uint(x2), b3 = __float_as_uint(x3);
      u[c4 * 4 + 0] = (b0 >> 31) ? ~b0 : (b0 | 0x80000000u);
      u[c4 * 4 + 1] = (b1 >> 31) ? ~b1 : (b1 | 0x80000000u);
      u[c4 * 4 + 2] = (b2 >> 31) ? ~b2 : (b2 | 0x80000000u);
      u[c4 * 4 + 3] = (b3 >> 31) ? ~b3 : (b3 | 0x80000000u);
    }
  }

  // kth largest of T~ (bit bisection) — unchanged
  unsigned lo = 0u;
  for (int bit = 31; bit >= 0; --bit) {
    unsigned cand = lo | (1u << bit);
    int cnt = 0;
#pragma unroll
    for (int c = 0; c < 32; ++c)
      cnt += (int)__popcll(__ballot(u[c] >= cand));
    if (cnt >= K) lo = cand;
  }
  const float t64 = dec_u(lo);

  // band classification — unchanged
  const float eps = 4e-3f;
  const float bhi = t64 + eps, blo = t64 - eps;
  int cnt_above = 0, cnt_band = 0;
#pragma unroll
  for (int c = 0; c < 32; ++c) {
    float f = dec_u(u[c]);
    cnt_above += (int)__popcll(__ballot(f > bhi));
    cnt_band  += (int)__popcll(__ballot(f <= bhi && f >= blo));
  }
  const int m = K - cnt_above;
  const bool refined = (cnt_band > m);
  int nm = 0;
  float kth = 3.4e38f;
  if (refined) {
    int myj = 0;
    for (int c = 0; c < 32 && nm < 32; ++c) {
      float f = dec_u(u[c]);
      unsigned long long ba = __ballot(f <= bhi && f >= blo);
      while (ba && nm < 32) {
        int src = __builtin_ctzll(ba); ba &= ba - 1ull;
        int j = src * 4 + 256 * (c >> 2) + (c & 3);
        if (nm == lane) myj = j;
        ++nm;
      }
    }
    float myval = -3.4e38f;
    if (lane < nm) myval = np_score(qg, kg, w_pre, bias, bb, g, ig, myj);
    if (lane < 32) repv_s[wv][lane] = (lane < nm) ? myval : -3.4e38f;
    unsigned chosen = 0;
    for (int s = 0; s < m && s < nm; ++s) {
      float best = -3.4e38f; int bi = -1;
      for (int i2 = 0; i2 < nm; ++i2) {
        if ((chosen >> i2) & 1u) continue;
        float bv = repv_s[wv][i2];
        if (bv > best) { best = bv; bi = i2; }
      }
      if (bi < 0) break;
      chosen |= (1u << bi);
      kth = best;
    }
  }

  // p values — identical math; p overlaid onto u in place
  float ssum = 0.f;
  int ord = 0;
#pragma unroll
  for (int c = 0; c < 32; ++c) {
    float f = dec_u(u[c]);
    float pv;
    if (refined) {
      bool above = f > bhi;
      bool inb = (!above) && (f >= blo);
      unsigned long long ba = __ballot(inb);
      int myord = ord + (int)__popcll(ba & ((1ull << lane) - 1ull));
      ord += (int)__popcll(ba);
      if (above) pv = 0.f;
      else if (inb) {
        if (myord < nm) {
          float val = repv_s[wv][myord];
          pv = (val >= kth) ? 0.f : __expf(val - t64);
        } else pv = 0.f;
      } else pv = __expf(f - t64);
    } else {
      pv = (f >= blo) ? 0.f : __expf(f - t64);
    }
    u[c] = __float_as_uint(pv);
    ssum += pv;
  }
  ssum = waveReduceSum(ssum);
  const float isv = 1.f / ssum;

  // store Pn = p * isv as f16, straight from registers
  __half* Ab = A + ((size_t)g * SI + il) * N_;
#pragma unroll
  for (int c = 0; c < 8; ++c) {
    int j = lane * 4 + 256 * c;
    float p0 = __uint_as_float(u[c * 4 + 0]) * isv;
    float p1 = __uint_as_float(u[c * 4 + 1]) * isv;
    float p2 = __uint_as_float(u[c * 4 + 2]) * isv;
    float p3 = __uint_as_float(u[c * 4 + 3]) * isv;
    *(__half2*)&Ab[j]     = __floats2half2_rn(p0, p1);
    *(__half2*)&Ab[j + 2] = __floats2half2_rn(p2, p3);
  }
}

// ---------------------------------------------------------------------------
// Pass 2b: A2[g][il][j] = f16( sum_h w_post[g,h] * f32(Pn[h][il][j]) )
// ---------------------------------------------------------------------------
__global__ __launch_bounds__(256) void postmixA_kernel(
    const __half* __restrict__ Pn, const float* __restrict__ w_post,
    __half* __restrict__ A2, int SI) {
  const int idx = blockIdx.x * 256 + threadIdx.x;   // over SI * (N/2)
  const int il = idx >> 10;                         // N/2 = 1024
  const int jc = (idx & 1023) * 2;
  float2 acc[16];
#pragma unroll
  for (int g = 0; g < 16; ++g) acc[g] = make_float2(0.f, 0.f);
#pragma unroll
  for (int h = 0; h < 16; ++h) {
    __half2 ph = *(const __half2*)&Pn[((size_t)h * SI + il) * N_ + jc];
    float2 pf = __half22float2(ph);
#pragma unroll
    for (int g = 0; g < 16; ++g) {
      const float w = w_post[g * 16 + h];
      acc[g].x = fmaf(w, pf.x, acc[g].x);
      acc[g].y = fmaf(w, pf.y, acc[g].y);
    }
  }
#pragma unroll
  for (int g = 0; g < 16; ++g)
    *(__half2*)&A2[((size_t)g * SI + il) * N_ + jc] =
        __floats2half2_rn(acc[g].x, acc[g].y);
}

// ---------------------------------------------------------------------------
// Pass 3: out[b,g,i0+i,:] = sum_j A2[g,i,j] * v[b,g,j,:]   (unchanged)
// ---------------------------------------------------------------------------
__global__ __launch_bounds__(256) void pv_kernel(
    const __half* __restrict__ A, const float* __restrict__ v,
    float* __restrict__ out, int bb, int i0, int SI) {
  const int it = blockIdx.x * 128;
  const int g  = blockIdx.y;
  const int t  = threadIdx.x;
  const int tx = t & 15, ty = t >> 4;
  __shared__ __half as_[128][72];
  __shared__ __half vt[64][72];
  float acc[8][4];
#pragma unroll
  for (int i = 0; i < 8; ++i)
#pragma unroll
    for (int j = 0; j < 4; ++j) acc[i][j] = 0.f;
  const float* vb = v + ((size_t)bb * H_ + g) * (size_t)N_ * D_;

  for (int kb = 0; kb < N_; kb += 64) {
#pragma unroll
    for (int l = 0; l < 4; ++l) {
      int e8 = t + l * 256;
      int row = e8 >> 3, c8 = e8 & 7;
      *(uint4*)&as_[row][c8 * 8] =
          *(const uint4*)&A[((size_t)g * SI + (it + row)) * N_ + kb + c8 * 8];
    }
#pragma unroll
    for (int l = 0; l < 4; ++l) {
      int e4 = t + l * 256;
      int row = e4 >> 4, d4 = e4 & 15;
      float4 x = *(const float4*)&vb[(size_t)(kb + row) * D_ + d4 * 4];
      vt[d4 * 4 + 0][row] = __float2half_rn(x.x);
      vt[d4 * 4 + 1][row] = __float2half_rn(x.y);
      vt[d4 * 4 + 2][row] = __float2half_rn(x.z);
      vt[d4 * 4 + 3][row] = __float2half_rn(x.w);
    }
    __syncthreads();
#pragma unroll
    for (int k8 = 0; k8 < 8; ++k8) {
      float vf[4][8];
#pragma unroll
      for (int dj = 0; dj < 4; ++dj) {
        const __half2* p2 = (const __half2*)&vt[dj * 16 + tx][k8 * 8];
#pragma unroll
        for (int c = 0; c < 4; ++c) {
          float2 f = __half22float2(p2[c]);
          vf[dj][c * 2] = f.x; vf[dj][c * 2 + 1] = f.y;
        }
      }
#pragma unroll
      for (int di = 0; di < 8; ++di) {
        const __half2* a2 = (const __half2*)&as_[di * 16 + ty][k8 * 8];
        float af2[8];
#pragma unroll
        for (int c = 0; c < 4; ++c) {
          float2 f = __half22float2(a2[c]);
          af2[c * 2] = f.x; af2[c * 2 + 1] = f.y;
        }
#pragma unroll
        for (int dj = 0; dj < 4; ++dj)
#pragma unroll
          for (int kk = 0; kk < 8; ++kk)
            acc[di][dj] = fmaf(af2[kk], vf[dj][kk], acc[di][dj]);
      }
    }
    __syncthreads();
  }
  float* ob = out + (((size_t)bb * H_ + g) * N_ + (size_t)(i0 + it)) * D_;
#pragma unroll
  for (int di = 0; di < 8; ++di)
#pragma unroll
    for (int dj = 0; dj < 4; ++dj)
      ob[(size_t)(di * 16 + ty) * D_ + dj * 16 + tx] = acc[di][dj];
}

// ---------------------------------------------------------------------------
extern "C" void kernel_launch(void* const* d_in, const int* in_sizes, int n_in,
                              void* d_out, int out_size, void* d_ws, size_t ws_size,
                              hipStream_t stream) {
  const float* q      = (const float*)d_in[0];
  const float* k      = (const float*)d_in[1];
  const float* v      = (const float*)d_in[2];
  const float* bias   = (const float*)d_in[3];
  const float* w_pre  = (const float*)d_in[4];
  const float* w_post = (const float*)d_in[5];
  const int*   topk   = (const int*)d_in[6];
  float* out = (float*)d_out;

  int SI = N_;
  while ((size_t)H_ * SI * N_ * 6 > ws_size && SI > 128) SI >>= 1;
  float*  Sbuf = (float*)d_ws;                                       // H*SI*N*4
  __half* Abuf = (__half*)((char*)d_ws + (size_t)H_ * SI * N_ * 4);  // Pn
  __half* A2   = (__half*)d_ws;   // aliases S region (S dead after mid)

  for (int b = 0; b < B_; ++b) {
    for (int i0 = 0; i0 < N_; i0 += SI) {
      qk_mfma<<<dim3(N_ / 64, SI / 64, H_), 256, 0, stream>>>(q, k, Sbuf, b, i0, SI);
      mid_kernel<<<dim3(SI * 4), 256, 0, stream>>>(Sbuf, Abuf, bias, w_pre,
                                                   topk, q, k, b, i0, SI);
      postmixA_kernel<<<dim3(SI * (N_ / 2) / 256), 256, 0, stream>>>(Abuf, w_post,
                                                                     A2, SI);
      pv_kernel<<<dim3(SI / 128, H_), 256, 0, stream>>>(A2, v, out, b, i0, SI);
    }
  }
}

// Round 18
// 1286.499 us; speedup vs baseline: 1.6831x; 1.6831x over previous
//
#include <hip/hip_runtime.h>
#include <hip/hip_fp16.h>

#define B_ 2
#define H_ 16
#define N_ 2048
#define D_ 64

typedef __attribute__((ext_vector_type(8))) __bf16 bf16x8;
typedef __attribute__((ext_vector_type(8))) _Float16 f16x8;
typedef __attribute__((ext_vector_type(4))) float f32x4;

__device__ __forceinline__ unsigned short f2bf_rn(float x) {
  unsigned u = __float_as_uint(x);
  unsigned r = (u + 0x7fffu + ((u >> 16) & 1u)) >> 16;
  return (unsigned short)r;
}
__device__ __forceinline__ float bf2f(unsigned short s) {
  return __uint_as_float(((unsigned)s) << 16);
}

// ---------------------------------------------------------------------------
// Pass 1 (fast approx): S~[h][il][j] = 0.125 * (q1k1 + q1k2 + q2k1) via bf16
// MFMA 16x16x32, f32 accumulate.  (unchanged — field-proven)
// ---------------------------------------------------------------------------
__global__ __launch_bounds__(256) void qk_mfma(
    const float* __restrict__ q, const float* __restrict__ k,
    float* __restrict__ S, int bb, int i0, int SI) {
  const int h  = blockIdx.z;
  const int it = blockIdx.y * 64;
  const int jt = blockIdx.x * 64;
  __shared__ unsigned short q1s[64][72], q2s[64][72];
  __shared__ unsigned short k1s[64][72], k2s[64][72];
  const int t = threadIdx.x;
  const float* qb = q + (((size_t)bb * H_ + h) * N_ + (size_t)(i0 + it)) * D_;
  const float* kb = k + (((size_t)bb * H_ + h) * N_ + (size_t)jt) * D_;
#pragma unroll
  for (int l = 0; l < 4; ++l) {
    int e4 = t + l * 256;
    int row = e4 >> 4, c4 = e4 & 15;
    float4 xq = *(const float4*)(qb + (size_t)row * D_ + c4 * 4);
    float4 xk = *(const float4*)(kb + (size_t)row * D_ + c4 * 4);
    float qa[4] = {xq.x, xq.y, xq.z, xq.w};
    float ka[4] = {xk.x, xk.y, xk.z, xk.w};
#pragma unroll
    for (int m = 0; m < 4; ++m) {
      unsigned short h1 = f2bf_rn(qa[m]);
      unsigned short h2 = f2bf_rn(qa[m] - bf2f(h1));
      q1s[row][c4 * 4 + m] = h1;
      q2s[row][c4 * 4 + m] = h2;
      unsigned short g1 = f2bf_rn(ka[m]);
      unsigned short g2 = f2bf_rn(ka[m] - bf2f(g1));
      k1s[row][c4 * 4 + m] = g1;
      k2s[row][c4 * 4 + m] = g2;
    }
  }
  __syncthreads();
  const int lane = t & 63, wv = t >> 6;
  const int lr = lane & 15;
  const int lk = (lane >> 4) * 8;
  const int arow = wv * 16 + lr;
  f32x4 acc[4];
#pragma unroll
  for (int ct = 0; ct < 4; ++ct) acc[ct] = (f32x4){0.f, 0.f, 0.f, 0.f};
#pragma unroll
  for (int ks = 0; ks < 2; ++ks) {
    bf16x8 a1 = *(const bf16x8*)&q1s[arow][ks * 32 + lk];
    bf16x8 a2 = *(const bf16x8*)&q2s[arow][ks * 32 + lk];
#pragma unroll
    for (int ct = 0; ct < 4; ++ct) {
      bf16x8 b1 = *(const bf16x8*)&k1s[ct * 16 + lr][ks * 32 + lk];
      bf16x8 b2 = *(const bf16x8*)&k2s[ct * 16 + lr][ks * 32 + lk];
      acc[ct] = __builtin_amdgcn_mfma_f32_16x16x32_bf16(a1, b1, acc[ct], 0, 0, 0);
      acc[ct] = __builtin_amdgcn_mfma_f32_16x16x32_bf16(a1, b2, acc[ct], 0, 0, 0);
      acc[ct] = __builtin_amdgcn_mfma_f32_16x16x32_bf16(a2, b1, acc[ct], 0, 0, 0);
    }
  }
#pragma unroll
  for (int ct = 0; ct < 4; ++ct)
#pragma unroll
    for (int r = 0; r < 4; ++r) {
      int row = it + wv * 16 + (lane >> 4) * 4 + r;
      int col = jt + ct * 16 + lr;
      S[((size_t)h * SI + row) * N_ + col] = acc[ct][r] * 0.125f;
    }
}

__device__ inline float waveReduceSum(float x) {
#pragma unroll
  for (int off = 32; off > 0; off >>= 1) x += __shfl_xor(x, off, 64);
  return x;
}

__device__ inline float dec_u(unsigned uu) {
  unsigned bbv = (uu >> 31) ? (uu & 0x7fffffffu) : ~uu;
  return __uint_as_float(bbv);
}

// ---------------------------------------------------------------------------
// EXACT referee replica (R8-proven AVX512-FMA tree), serial in one lane.
// R16 scalar-load version (VGPR-lean — R17's float4 variant cost 48 regs).
// ---------------------------------------------------------------------------
__device__ float np_score(
    const float* __restrict__ qg, const float* __restrict__ kg,
    const float* __restrict__ w_pre, const float* __restrict__ bias,
    int bb, int g, int ig, int j) {
  float T = 0.f;
  for (int h = 0; h < 16; ++h) {
    const float* qr = qg + (((size_t)bb * H_ + h) * N_ + ig) * (size_t)D_;
    const float* kr = kg + (((size_t)bb * H_ + h) * N_ + j) * (size_t)D_;
    float lacc[16];
#pragma unroll
    for (int l = 0; l < 16; ++l) {
      float tt = __fmul_rn(qr[48 + l], kr[48 + l]);
      tt = __fmaf_rn(qr[32 + l], kr[32 + l], tt);
      tt = __fmaf_rn(qr[16 + l], kr[16 + l], tt);
      tt = __fmaf_rn(qr[l], kr[l], tt);
      lacc[l] = tt;
    }
    float u8[8];
#pragma unroll
    for (int l2 = 0; l2 < 8; ++l2) u8[l2] = __fadd_rn(lacc[l2], lacc[l2 + 8]);
    float u4[4];
#pragma unroll
    for (int l2 = 0; l2 < 4; ++l2) u4[l2] = __fadd_rn(u8[l2], u8[l2 + 4]);
    float dot = __fadd_rn(__fadd_rn(u4[0], u4[2]), __fadd_rn(u4[1], u4[3]));
    T = __fmaf_rn(w_pre[g * 16 + h], __fmul_rn(dot, 0.125f), T);
  }
  return __fadd_rn(T, bias[((size_t)g * N_ + ig) * N_ + j]);
}

// ---------------------------------------------------------------------------
// Pass 2 (v18 = R16 body, grid transposed): grid (4, SI), blockIdx.x = g
// quarter (fastest-varying -> the 4 quarters of an il dispatch adjacently,
// S rows stay L2/L3-hot). Arithmetic/mapping bit-identical to R16.
// ---------------------------------------------------------------------------
__global__ __launch_bounds__(256) void mid_kernel(
    const float* __restrict__ S, __half* __restrict__ A,
    const float* __restrict__ bias,
    const float* __restrict__ w_pre,
    const int* __restrict__ topk_p,
    const float* __restrict__ qg, const float* __restrict__ kg,
    int bb, int i0, int SI) {
  const int il = blockIdx.y;
  const int ig = i0 + il;
  const int t = threadIdx.x;
  const int lane = t & 63, wv = t >> 6;
  const int g = blockIdx.x * 4 + wv;
  const int K = *topk_p;
  __shared__ float repv_s[4][32];

  // ---- mix: stream h, accumulate 32 cols in registers ----
  float af[32];
#pragma unroll
  for (int c = 0; c < 32; ++c) af[c] = 0.f;
#pragma unroll 1
  for (int h = 0; h < 16; ++h) {
    const float w = w_pre[g * 16 + h];
    const float* Sr = S + ((size_t)h * SI + il) * N_;
#pragma unroll
    for (int c4 = 0; c4 < 8; ++c4) {
      float4 s4 = *(const float4*)&Sr[lane * 4 + 256 * c4];
      af[c4 * 4 + 0] = __fmaf_rn(w, s4.x, af[c4 * 4 + 0]);
      af[c4 * 4 + 1] = __fmaf_rn(w, s4.y, af[c4 * 4 + 1]);
      af[c4 * 4 + 2] = __fmaf_rn(w, s4.z, af[c4 * 4 + 2]);
      af[c4 * 4 + 3] = __fmaf_rn(w, s4.w, af[c4 * 4 + 3]);
    }
  }
  unsigned u[32];
  {
    const float* Br = bias + ((size_t)g * N_ + ig) * N_;
#pragma unroll
    for (int c4 = 0; c4 < 8; ++c4) {
      float4 bv = *(const float4*)&Br[lane * 4 + 256 * c4];
      float x0 = __fadd_rn(af[c4 * 4 + 0], bv.x);
      float x1 = __fadd_rn(af[c4 * 4 + 1], bv.y);
      float x2 = __fadd_rn(af[c4 * 4 + 2], bv.z);
      float x3 = __fadd_rn(af[c4 * 4 + 3], bv.w);
      unsigned b0 = __float_as_uint(x0), b1 = __float_as_uint(x1);
      unsigned b2 = __float_as_uint(x2), b3 = __float_as_uint(x3);
      u[c4 * 4 + 0] = (b0 >> 31) ? ~b0 : (b0 | 0x80000000u);
      u[c4 * 4 + 1] = (b1 >> 31) ? ~b1 : (b1 | 0x80000000u);
      u[c4 * 4 + 2] = (b2 >> 31) ? ~b2 : (b2 | 0x80000000u);
      u[c4 * 4 + 3] = (b3 >> 31) ? ~b3 : (b3 | 0x80000000u);
    }
  }

  // kth largest of T~ (bit bisection) — unchanged
  unsigned lo = 0u;
  for (int bit = 31; bit >= 0; --bit) {
    unsigned cand = lo | (1u << bit);
    int cnt = 0;
#pragma unroll
    for (int c = 0; c < 32; ++c)
      cnt += (int)__popcll(__ballot(u[c] >= cand));
    if (cnt >= K) lo = cand;
  }
  const float t64 = dec_u(lo);

  // band classification — unchanged
  const float eps = 4e-3f;
  const float bhi = t64 + eps, blo = t64 - eps;
  int cnt_above = 0, cnt_band = 0;
#pragma unroll
  for (int c = 0; c < 32; ++c) {
    float f = dec_u(u[c]);
    cnt_above += (int)__popcll(__ballot(f > bhi));
    cnt_band  += (int)__popcll(__ballot(f <= bhi && f >= blo));
  }
  const int m = K - cnt_above;
  const bool refined = (cnt_band > m);
  int nm = 0;
  float kth = 3.4e38f;
  if (refined) {
    int myj = 0;
    for (int c = 0; c < 32 && nm < 32; ++c) {
      float f = dec_u(u[c]);
      unsigned long long ba = __ballot(f <= bhi && f >= blo);
      while (ba && nm < 32) {
        int src = __builtin_ctzll(ba); ba &= ba - 1ull;
        int j = src * 4 + 256 * (c >> 2) + (c & 3);
        if (nm == lane) myj = j;
        ++nm;
      }
    }
    float myval = -3.4e38f;
    if (lane < nm) myval = np_score(qg, kg, w_pre, bias, bb, g, ig, myj);
    if (lane < 32) repv_s[wv][lane] = (lane < nm) ? myval : -3.4e38f;
    unsigned chosen = 0;
    for (int s = 0; s < m && s < nm; ++s) {
      float best = -3.4e38f; int bi = -1;
      for (int i2 = 0; i2 < nm; ++i2) {
        if ((chosen >> i2) & 1u) continue;
        float bv = repv_s[wv][i2];
        if (bv > best) { best = bv; bi = i2; }
      }
      if (bi < 0) break;
      chosen |= (1u << bi);
      kth = best;
    }
  }

  // p values — identical math; p overlaid onto u in place
  float ssum = 0.f;
  int ord = 0;
#pragma unroll
  for (int c = 0; c < 32; ++c) {
    float f = dec_u(u[c]);
    float pv;
    if (refined) {
      bool above = f > bhi;
      bool inb = (!above) && (f >= blo);
      unsigned long long ba = __ballot(inb);
      int myord = ord + (int)__popcll(ba & ((1ull << lane) - 1ull));
      ord += (int)__popcll(ba);
      if (above) pv = 0.f;
      else if (inb) {
        if (myord < nm) {
          float val = repv_s[wv][myord];
          pv = (val >= kth) ? 0.f : __expf(val - t64);
        } else pv = 0.f;
      } else pv = __expf(f - t64);
    } else {
      pv = (f >= blo) ? 0.f : __expf(f - t64);
    }
    u[c] = __float_as_uint(pv);
    ssum += pv;
  }
  ssum = waveReduceSum(ssum);
  const float isv = 1.f / ssum;

  // store Pn = p * isv as f16, straight from registers
  __half* Ab = A + ((size_t)g * SI + il) * N_;
#pragma unroll
  for (int c = 0; c < 8; ++c) {
    int j = lane * 4 + 256 * c;
    float p0 = __uint_as_float(u[c * 4 + 0]) * isv;
    float p1 = __uint_as_float(u[c * 4 + 1]) * isv;
    float p2 = __uint_as_float(u[c * 4 + 2]) * isv;
    float p3 = __uint_as_float(u[c * 4 + 3]) * isv;
    *(__half2*)&Ab[j]     = __floats2half2_rn(p0, p1);
    *(__half2*)&Ab[j + 2] = __floats2half2_rn(p2, p3);
  }
}

// ---------------------------------------------------------------------------
// Pass 2b: A2[g][il][j] = f16( sum_h w_post[g,h] * f32(Pn[h][il][j]) )
// ---------------------------------------------------------------------------
__global__ __launch_bounds__(256) void postmixA_kernel(
    const __half* __restrict__ Pn, const float* __restrict__ w_post,
    __half* __restrict__ A2, int SI) {
  const int idx = blockIdx.x * 256 + threadIdx.x;   // over SI * (N/2)
  const int il = idx >> 10;                         // N/2 = 1024
  const int jc = (idx & 1023) * 2;
  float2 acc[16];
#pragma unroll
  for (int g = 0; g < 16; ++g) acc[g] = make_float2(0.f, 0.f);
#pragma unroll
  for (int h = 0; h < 16; ++h) {
    __half2 ph = *(const __half2*)&Pn[((size_t)h * SI + il) * N_ + jc];
    float2 pf = __half22float2(ph);
#pragma unroll
    for (int g = 0; g < 16; ++g) {
      const float w = w_post[g * 16 + h];
      acc[g].x = fmaf(w, pf.x, acc[g].x);
      acc[g].y = fmaf(w, pf.y, acc[g].y);
    }
  }
#pragma unroll
  for (int g = 0; g < 16; ++g)
    *(__half2*)&A2[((size_t)g * SI + il) * N_ + jc] =
        __floats2half2_rn(acc[g].x, acc[g].y);
}

// ---------------------------------------------------------------------------
// Pass 3 (v18): MFMA f16 PV.  out[b,g,i0+i,:] = sum_j A2[g,i,j] * v[b,g,j,:]
// Same staging as before (as_[128][72], vt[64][72] f16); inner compute is
// mfma_f32_16x16x32_f16 with the field-proven fragment layout.
// Wave wv owns rows [32wv, 32wv+32): acc[2 row-tiles][4 d-tiles] f32x4.
// ---------------------------------------------------------------------------
__global__ __launch_bounds__(256) void pv_kernel(
    const __half* __restrict__ A, const float* __restrict__ v,
    float* __restrict__ out, int bb, int i0, int SI) {
  const int it = blockIdx.x * 128;
  const int g  = blockIdx.y;
  const int t  = threadIdx.x;
  const int lane = t & 63, wv = t >> 6;
  const int lr = lane & 15;
  const int hi = lane >> 4;
  const int lk = hi * 8;
  __shared__ __half as_[128][72];
  __shared__ __half vt[64][72];
  f32x4 acc[2][4];
#pragma unroll
  for (int rt = 0; rt < 2; ++rt)
#pragma unroll
    for (int ct = 0; ct < 4; ++ct) acc[rt][ct] = (f32x4){0.f, 0.f, 0.f, 0.f};
  const float* vb = v + ((size_t)bb * H_ + g) * (size_t)N_ * D_;

  for (int kb = 0; kb < N_; kb += 64) {
#pragma unroll
    for (int l = 0; l < 4; ++l) {
      int e8 = t + l * 256;
      int row = e8 >> 3, c8 = e8 & 7;
      *(uint4*)&as_[row][c8 * 8] =
          *(const uint4*)&A[((size_t)g * SI + (it + row)) * N_ + kb + c8 * 8];
    }
#pragma unroll
    for (int l = 0; l < 4; ++l) {
      int e4 = t + l * 256;
      int row = e4 >> 4, d4 = e4 & 15;
      float4 x = *(const float4*)&vb[(size_t)(kb + row) * D_ + d4 * 4];
      vt[d4 * 4 + 0][row] = __float2half_rn(x.x);
      vt[d4 * 4 + 1][row] = __float2half_rn(x.y);
      vt[d4 * 4 + 2][row] = __float2half_rn(x.z);
      vt[d4 * 4 + 3][row] = __float2half_rn(x.w);
    }
    __syncthreads();
#pragma unroll
    for (int ks = 0; ks < 2; ++ks) {
      f16x8 a0 = *(const f16x8*)&as_[wv * 32 + lr][ks * 32 + lk];
      f16x8 a1 = *(const f16x8*)&as_[wv * 32 + 16 + lr][ks * 32 + lk];
#pragma unroll
      for (int ct = 0; ct < 4; ++ct) {
        f16x8 bv = *(const f16x8*)&vt[ct * 16 + lr][ks * 32 + lk];
        acc[0][ct] = __builtin_amdgcn_mfma_f32_16x16x32_f16(a0, bv, acc[0][ct], 0, 0, 0);
        acc[1][ct] = __builtin_amdgcn_mfma_f32_16x16x32_f16(a1, bv, acc[1][ct], 0, 0, 0);
      }
    }
    __syncthreads();
  }
  float* ob = out + (((size_t)bb * H_ + g) * N_ + (size_t)(i0 + it)) * D_;
#pragma unroll
  for (int rt = 0; rt < 2; ++rt)
#pragma unroll
    for (int ct = 0; ct < 4; ++ct)
#pragma unroll
      for (int r = 0; r < 4; ++r)
        ob[(size_t)(wv * 32 + rt * 16 + hi * 4 + r) * D_ + ct * 16 + lr] =
            acc[rt][ct][r];
}

// ---------------------------------------------------------------------------
extern "C" void kernel_launch(void* const* d_in, const int* in_sizes, int n_in,
                              void* d_out, int out_size, void* d_ws, size_t ws_size,
                              hipStream_t stream) {
  const float* q      = (const float*)d_in[0];
  const float* k      = (const float*)d_in[1];
  const float* v      = (const float*)d_in[2];
  const float* bias   = (const float*)d_in[3];
  const float* w_pre  = (const float*)d_in[4];
  const float* w_post = (const float*)d_in[5];
  const int*   topk   = (const int*)d_in[6];
  float* out = (float*)d_out;

  int SI = N_;
  while ((size_t)H_ * SI * N_ * 6 > ws_size && SI > 128) SI >>= 1;
  float*  Sbuf = (float*)d_ws;                                       // H*SI*N*4
  __half* Abuf = (__half*)((char*)d_ws + (size_t)H_ * SI * N_ * 4);  // Pn
  __half* A2   = (__half*)d_ws;   // aliases S region (S dead after mid)

  for (int b = 0; b < B_; ++b) {
    for (int i0 = 0; i0 < N_; i0 += SI) {
      qk_mfma<<<dim3(N_ / 64, SI / 64, H_), 256, 0, stream>>>(q, k, Sbuf, b, i0, SI);
      mid_kernel<<<dim3(4, SI), 256, 0, stream>>>(Sbuf, Abuf, bias, w_pre,
                                                  topk, q, k, b, i0, SI);
      postmixA_kernel<<<dim3(SI * (N_ / 2) / 256), 256, 0, stream>>>(Abuf, w_post,
                                                                     A2, SI);
      pv_kernel<<<dim3(SI / 128, H_), 256, 0, stream>>>(A2, v, out, b, i0, SI);
    }
  }
}